// Round 13
// baseline (772.902 us; speedup 1.0000x reference)
//
#include <hip/hip_runtime.h>

#define N_NODES 50000
#define N_EDGES 800000
#define N_GRAPHS 2048
#define IN_DIM 128
#define HID 256
#define N_LAYERS 4
#define BN_EPS 1e-5f
#define NBIN 128

typedef unsigned short ushort_t;
typedef __bf16 bf16x8 __attribute__((ext_vector_type(8)));
typedef float f32x4 __attribute__((ext_vector_type(4)));
typedef unsigned int u32x2 __attribute__((ext_vector_type(2)));

// ---- fp32 -> bf16 (round-to-nearest-even) helpers ----
__device__ __forceinline__ ushort_t f2bf_rn(float x) {
    unsigned int u = __float_as_uint(x);
    u += 0x7FFFu + ((u >> 16) & 1u);
    return (ushort_t)(u >> 16);
}
__device__ __forceinline__ float bf2f(ushort_t h) {
    return __uint_as_float(((unsigned int)h) << 16);
}

// ---- async global->LDS, 16B per lane ----
__device__ __forceinline__ void gl_lds16(const ushort_t* g, ushort_t* l) {
    __builtin_amdgcn_global_load_lds(
        (const __attribute__((address_space(1))) void*)g,
        (__attribute__((address_space(3))) void*)l, 16, 0, 0);
}

// ---------------- degree count ----------------
__global__ void k_deg(const int* __restrict__ dst, int* __restrict__ degi, int E) {
    int e = blockIdx.x * blockDim.x + threadIdx.x;
    if (e < E) atomicAdd(&degi[dst[e]], 1);
}

__global__ void k_nodenorm(const int* __restrict__ degi, float* __restrict__ dinv,
                           float* __restrict__ selfn, int N) {
    int n = blockIdx.x * blockDim.x + threadIdx.x;
    if (n < N) {
        float d = 1.0f + (float)degi[n];
        dinv[n] = 1.0f / sqrtf(d);
        selfn[n] = 1.0f / d;
    }
}

// ---------------- degree histogram (hierarchical) ----------------
__global__ __launch_bounds__(256) void k_hist(const int* __restrict__ degi,
                                              int* __restrict__ bins, int N) {
    __shared__ int lbin[NBIN];
    int t = threadIdx.x;
    if (t < NBIN) lbin[t] = 0;
    __syncthreads();
    int n = blockIdx.x * 256 + t;
    if (n < N) atomicAdd(&lbin[min(degi[n], NBIN - 1)], 1);
    __syncthreads();
    if (t < NBIN && lbin[t] > 0) atomicAdd(&bins[t], lbin[t]);
}

// ---------------- bin prefix (tiny serial, 128 iters) ----------------
__global__ void k_binscan(const int* __restrict__ bins, int* __restrict__ binstart,
                          int* __restrict__ bincur, int* __restrict__ edgebase) {
    if (threadIdx.x == 0) {
        int run = 0, erun = 0;
        for (int d = 0; d < NBIN; ++d) {
            binstart[d] = run;
            bincur[d] = run;
            edgebase[d] = erun;
            run += bins[d];
            erun += bins[d] * d;
        }
    }
}

// ---------------- parallel slot assignment, hierarchical; emits per-slot meta ----------------
// Bin-d edges stored COLUMN-MAJOR: edge j of slot s at edgebase[d] + j*bins[d] + (s-binstart[d]).
// meta[slot] = { eoff, stride | deg<<20 }.
__global__ __launch_bounds__(256) void k_assign(const int* __restrict__ degi,
                                                const int* __restrict__ binstart,
                                                const int* __restrict__ edgebase,
                                                const int* __restrict__ bins,
                                                int* __restrict__ bincur,
                                                int* __restrict__ perm, int* __restrict__ invperm,
                                                int2* __restrict__ meta, int* __restrict__ cursor,
                                                int N) {
    __shared__ int lbin[NBIN];
    __shared__ int lbase[NBIN];
    int t = threadIdx.x;
    if (t < NBIN) lbin[t] = 0;
    __syncthreads();
    int n = blockIdx.x * 256 + t;
    int d = 0, lrank = 0;
    if (n < N) {
        d = min(degi[n], NBIN - 1);
        lrank = atomicAdd(&lbin[d], 1);
    }
    __syncthreads();
    if (t < NBIN && lbin[t] > 0) lbase[t] = atomicAdd(&bincur[t], lbin[t]);
    __syncthreads();
    if (n < N) {
        int slot = lbase[d] + lrank;
        perm[slot] = n;
        invperm[n] = slot;
        int2 m;
        m.x = edgebase[d] + (slot - binstart[d]);
        m.y = bins[d] | (d << 20);
        meta[slot] = m;
        cursor[slot] = 0;
    }
}

// ---------------- CSR fill into bin-interleaved layout ----------------
__global__ void k_fill(const int* __restrict__ src, const int* __restrict__ dst,
                       const float* __restrict__ dinv, const int* __restrict__ invperm,
                       const int2* __restrict__ meta, int* __restrict__ cursor,
                       int2* __restrict__ edata, int E) {
    int e = blockIdx.x * blockDim.x + threadIdx.x;
    if (e >= E) return;
    int s = src[e], d = dst[e];
    int slot = invperm[d];
    int2 m = meta[slot];
    int j = atomicAdd(&cursor[slot], 1);
    int pos = m.x + j * (m.y & 0xFFFFF);
    int2 v;
    v.x = s;
    v.y = __float_as_int(dinv[s] * dinv[d]);
    edata[pos] = v;
}

// ---------------- split x -> bf16 hi/lo ----------------
__global__ __launch_bounds__(256) void k_splitx(const float* __restrict__ x,
                                                ushort_t* __restrict__ Ah,
                                                ushort_t* __restrict__ Al, int total4) {
    int i = blockIdx.x * blockDim.x + threadIdx.x;
    if (i >= total4) return;
    float4 v = ((const float4*)x)[i];
    ushort4 h, l;
    h.x = f2bf_rn(v.x); l.x = f2bf_rn(v.x - bf2f(h.x));
    h.y = f2bf_rn(v.y); l.y = f2bf_rn(v.y - bf2f(h.y));
    h.z = f2bf_rn(v.z); l.z = f2bf_rn(v.z - bf2f(h.z));
    h.w = f2bf_rn(v.w); l.w = f2bf_rn(v.w - bf2f(h.w));
    ((ushort4*)Ah)[i] = h;
    ((ushort4*)Al)[i] = l;
}

// ---------------- split + transpose weights ----------------
__global__ void k_splitw(const float* __restrict__ W0, const float* __restrict__ Ws,
                         ushort_t* __restrict__ Wh, ushort_t* __restrict__ Wl) {
    int i = blockIdx.x * blockDim.x + threadIdx.x;
    const int total = 128 * 256 + 3 * 256 * 256;
    if (i >= total) return;
    float v;
    if (i < 32768) {
        int n = i >> 7, k = i & 127;
        v = W0[k * 256 + n];
    } else {
        int t = i - 32768;
        int l = t >> 16;
        int r = t & 65535;
        int n = r >> 8, k = r & 255;
        v = Ws[l * 65536 + k * 256 + n];
    }
    ushort_t h = f2bf_rn(v);
    Wh[i] = h;
    Wl[i] = f2bf_rn(v - bf2f(h));
}

// ---------------- MFMA split-bf16 GEMM (chunk-major output) ----------------
__global__ __launch_bounds__(256) void k_gemm(const ushort_t* __restrict__ Ah,
                                              const ushort_t* __restrict__ Al,
                                              const ushort_t* __restrict__ Wh,
                                              const ushort_t* __restrict__ Wl,
                                              float* __restrict__ H, int K) {
    __shared__ ushort_t sm[4 * 128 * 32];
    ushort_t* tAh = sm;
    ushort_t* tAl = sm + 4096;
    ushort_t* tWh = sm + 8192;
    ushort_t* tWl = sm + 12288;

    int tid = threadIdx.x;
    int lane = tid & 63;
    int w = tid >> 6;
    int wrow = w & 1, wcol = w >> 1;
    int row0 = blockIdx.x * 128;
    int col0 = blockIdx.y * 128;

    const ushort_t* gsrc = (w == 0) ? Ah : (w == 1) ? Al : (w == 2) ? Wh : Wl;
    int rbase = (w < 2) ? row0 : col0;
    int rlimit = (w < 2) ? N_NODES : (col0 + 128);
    ushort_t* ldst = sm + w * 4096;
    int srow = lane >> 2;
    int sch = lane & 3;

    f32x4 acc[4][4] = {};
    int m = lane & 15, q = lane >> 4;

    for (int k0 = 0; k0 < K; k0 += 32) {
        #pragma unroll
        for (int i = 0; i < 8; ++i) {
            int r = i * 16 + srow;
            int grow = rbase + r;
            int gch = sch ^ (r & 3);
            if (grow < rlimit)
                gl_lds16(gsrc + (size_t)grow * K + k0 + gch * 8, ldst + i * 512);
        }
        __syncthreads();

        bf16x8 ahf[4], alf[4], whf[4], wlf[4];
        #pragma unroll
        for (int r = 0; r < 4; ++r) {
            int rr = wrow * 64 + r * 16 + m;
            int off = rr * 32 + ((q ^ (rr & 3)) << 3);
            ahf[r] = *(const bf16x8*)(tAh + off);
            alf[r] = *(const bf16x8*)(tAl + off);
        }
        #pragma unroll
        for (int c = 0; c < 4; ++c) {
            int nn = wcol * 64 + c * 16 + m;
            int off = nn * 32 + ((q ^ (nn & 3)) << 3);
            whf[c] = *(const bf16x8*)(tWh + off);
            wlf[c] = *(const bf16x8*)(tWl + off);
        }
        #pragma unroll
        for (int r = 0; r < 4; ++r)
            #pragma unroll
            for (int c = 0; c < 4; ++c) {
                acc[r][c] = __builtin_amdgcn_mfma_f32_16x16x32_bf16(ahf[r], whf[c], acc[r][c], 0, 0, 0);
                acc[r][c] = __builtin_amdgcn_mfma_f32_16x16x32_bf16(ahf[r], wlf[c], acc[r][c], 0, 0, 0);
                acc[r][c] = __builtin_amdgcn_mfma_f32_16x16x32_bf16(alf[r], whf[c], acc[r][c], 0, 0, 0);
            }
        __syncthreads();
    }

    #pragma unroll
    for (int r = 0; r < 4; ++r) {
        int mrow = row0 + wrow * 64 + r * 16 + (lane >> 4) * 4;
        #pragma unroll
        for (int c = 0; c < 4; ++c) {
            int n = col0 + wcol * 64 + c * 16 + (lane & 15);
            float* base = H + (size_t)(n >> 4) * (N_NODES * 16) + (n & 15);
            f32x4 v = acc[r][c];
            #pragma unroll
            for (int g = 0; g < 4; ++g)
                if (mrow + g < N_NODES)
                    base[(size_t)(mrow + g) * 16] = v[g];
        }
    }
}

// ---------------- BN prep (bias folded) ----------------
__global__ void k_bnprep(const float* __restrict__ gamma, const float* __restrict__ beta,
                         const float* __restrict__ mean, const float* __restrict__ var,
                         const float* __restrict__ bias,
                         float* __restrict__ scale, float* __restrict__ shift) {
    int l = blockIdx.x;
    int c = threadIdx.x;
    if (c < HID) {
        float s = gamma[l * HID + c] * rsqrtf(var[l * HID + c] + BN_EPS);
        scale[l * HID + c] = s;
        shift[l * HID + c] = beta[l * HID + c] + (bias[l * HID + c] - mean[l * HID + c]) * s;
    }
}

// ---------------- chunked gather: XCD-affine slices, sorted slots, dual-slot chains ----------------
// One chunk per block (3.2 MB slice in XCD L2). Each thread handles slots s and s+64:
// two independent edge chains -> 8 outstanding H loads. deg(s+64) >= deg(s) (sorted).
#define GNB2 391  // ceil(50000/128) slot-blocks per chunk

#define EFMA(E, V, A) \
    { float wg = __int_as_float(E.y); \
      A.x = fmaf(V.x, wg, A.x); A.y = fmaf(V.y, wg, A.y); \
      A.z = fmaf(V.z, wg, A.z); A.w = fmaf(V.w, wg, A.w); }

__device__ __forceinline__ void gather_dual(const float* __restrict__ Hc,
                                            const int2* __restrict__ edata,
                                            int2 m0, int2 m1, int node0, int node1,
                                            float sn0, float sn1, int q4, bool has1,
                                            float4& acc0, float4& acc1) {
    int str0 = m0.y & 0xFFFFF, deg0 = m0.y >> 20;
    int str1 = m1.y & 0xFFFFF, deg1 = m1.y >> 20;
    const int2* ep0 = edata + m0.x;
    const int2* ep1 = edata + m1.x;
    float4 h0 = *(const float4*)(Hc + (size_t)node0 * 16 + q4);
    acc0.x = h0.x * sn0; acc0.y = h0.y * sn0; acc0.z = h0.z * sn0; acc0.w = h0.w * sn0;
    acc1 = make_float4(0.f, 0.f, 0.f, 0.f);
    if (has1) {
        float4 h1 = *(const float4*)(Hc + (size_t)node1 * 16 + q4);
        acc1.x = h1.x * sn1; acc1.y = h1.y * sn1; acc1.z = h1.z * sn1; acc1.w = h1.w * sn1;
    } else {
        deg1 = 0;
    }
    int dmin = min(deg0, deg1);
    int j = 0;
    // common prefix: both chains, unroll 4 => 8 outstanding H loads
    for (; j + 3 < dmin; j += 4) {
        int2 e0 = ep0[(size_t)(j + 0) * str0];
        int2 e1 = ep0[(size_t)(j + 1) * str0];
        int2 e2 = ep0[(size_t)(j + 2) * str0];
        int2 e3 = ep0[(size_t)(j + 3) * str0];
        int2 f0 = ep1[(size_t)(j + 0) * str1];
        int2 f1 = ep1[(size_t)(j + 1) * str1];
        int2 f2 = ep1[(size_t)(j + 2) * str1];
        int2 f3 = ep1[(size_t)(j + 3) * str1];
        float4 a0 = *(const float4*)(Hc + (size_t)e0.x * 16 + q4);
        float4 a1 = *(const float4*)(Hc + (size_t)e1.x * 16 + q4);
        float4 a2 = *(const float4*)(Hc + (size_t)e2.x * 16 + q4);
        float4 a3 = *(const float4*)(Hc + (size_t)e3.x * 16 + q4);
        float4 b0 = *(const float4*)(Hc + (size_t)f0.x * 16 + q4);
        float4 b1 = *(const float4*)(Hc + (size_t)f1.x * 16 + q4);
        float4 b2 = *(const float4*)(Hc + (size_t)f2.x * 16 + q4);
        float4 b3 = *(const float4*)(Hc + (size_t)f3.x * 16 + q4);
        EFMA(e0, a0, acc0) EFMA(e1, a1, acc0) EFMA(e2, a2, acc0) EFMA(e3, a3, acc0)
        EFMA(f0, b0, acc1) EFMA(f1, b1, acc1) EFMA(f2, b2, acc1) EFMA(f3, b3, acc1)
    }
    for (; j < dmin; ++j) {
        int2 e0 = ep0[(size_t)j * str0];
        int2 f0 = ep1[(size_t)j * str1];
        float4 a0 = *(const float4*)(Hc + (size_t)e0.x * 16 + q4);
        float4 b0 = *(const float4*)(Hc + (size_t)f0.x * 16 + q4);
        EFMA(e0, a0, acc0) EFMA(f0, b0, acc1)
    }
    // chain-0 remainder (when deg0 > deg1 impossible by sort, but keep for safety)
    for (; j < deg0; ++j) {
        int2 e0 = ep0[(size_t)j * str0];
        float4 a0 = *(const float4*)(Hc + (size_t)e0.x * 16 + q4);
        EFMA(e0, a0, acc0)
    }
    // chain-1 remainder, unroll 4
    int k = dmin;
    for (; k + 3 < deg1; k += 4) {
        int2 f0 = ep1[(size_t)(k + 0) * str1];
        int2 f1 = ep1[(size_t)(k + 1) * str1];
        int2 f2 = ep1[(size_t)(k + 2) * str1];
        int2 f3 = ep1[(size_t)(k + 3) * str1];
        float4 b0 = *(const float4*)(Hc + (size_t)f0.x * 16 + q4);
        float4 b1 = *(const float4*)(Hc + (size_t)f1.x * 16 + q4);
        float4 b2 = *(const float4*)(Hc + (size_t)f2.x * 16 + q4);
        float4 b3 = *(const float4*)(Hc + (size_t)f3.x * 16 + q4);
        EFMA(f0, b0, acc1) EFMA(f1, b1, acc1) EFMA(f2, b2, acc1) EFMA(f3, b3, acc1)
    }
    for (; k < deg1; ++k) {
        int2 f0 = ep1[(size_t)k * str1];
        float4 b0 = *(const float4*)(Hc + (size_t)f0.x * 16 + q4);
        EFMA(f0, b0, acc1)
    }
}

__device__ __forceinline__ float4 bn_relu(float4 a, float4 sc, float4 sh) {
    float4 o;
    o.x = fmaxf(fmaf(a.x, sc.x, sh.x), 0.f);
    o.y = fmaxf(fmaf(a.y, sc.y, sh.y), 0.f);
    o.z = fmaxf(fmaf(a.z, sc.z, sh.z), 0.f);
    o.w = fmaxf(fmaf(a.w, sc.w, sh.w), 0.f);
    return o;
}

__device__ __forceinline__ void store_bf_quad(float4 o, ushort_t* __restrict__ Xh,
                                              ushort_t* __restrict__ Xl, size_t oi) {
    ushort4 h, l;
    h.x = f2bf_rn(o.x); l.x = f2bf_rn(o.x - bf2f(h.x));
    h.y = f2bf_rn(o.y); l.y = f2bf_rn(o.y - bf2f(h.y));
    h.z = f2bf_rn(o.z); l.z = f2bf_rn(o.z - bf2f(h.z));
    h.w = f2bf_rn(o.w); l.w = f2bf_rn(o.w - bf2f(h.w));
    u32x2 hv, lv;
    hv.x = ((unsigned int)h.y << 16) | h.x;
    hv.y = ((unsigned int)h.w << 16) | h.z;
    lv.x = ((unsigned int)l.y << 16) | l.x;
    lv.y = ((unsigned int)l.w << 16) | l.z;
    __builtin_nontemporal_store(hv, (u32x2*)(Xh + oi));
    __builtin_nontemporal_store(lv, (u32x2*)(Xl + oi));
}

// variant A: bf16 hi/lo node-major (feeds next GEMM)
__global__ __launch_bounds__(256) void k_gather_bf(const float* __restrict__ H,
                                                   const int2* __restrict__ meta,
                                                   const int2* __restrict__ edata,
                                                   const int* __restrict__ perm,
                                                   const float* __restrict__ selfn,
                                                   const float* __restrict__ bnscale,
                                                   const float* __restrict__ bnshift,
                                                   ushort_t* __restrict__ Xh,
                                                   ushort_t* __restrict__ Xl) {
    int bid = blockIdx.x;
    int x8 = bid & 7;
    int rest = bid >> 3;
    int phase = (rest >= GNB2) ? 1 : 0;
    int nb = rest - phase * GNB2;
    int chunk = phase * 8 + x8;
    const float* Hc = H + (size_t)chunk * (N_NODES * 16);
    int lanegrp = threadIdx.x >> 2;           // 0..63
    int slot0 = nb * 128 + lanegrp;
    int slot1 = slot0 + 64;
    if (slot0 >= N_NODES) return;
    bool has1 = (slot1 < N_NODES);
    int node0 = perm[slot0];
    int node1 = has1 ? perm[slot1] : 0;
    int2 m0 = meta[slot0];
    int2 m1 = has1 ? meta[slot1] : make_int2(0, 0);
    float sn0 = selfn[node0];
    float sn1 = has1 ? selfn[node1] : 0.f;
    int q4 = (threadIdx.x & 3) * 4;
    float4 sc = *(const float4*)(bnscale + chunk * 16 + q4);
    float4 sh = *(const float4*)(bnshift + chunk * 16 + q4);
    float4 acc0, acc1;
    gather_dual(Hc, edata, m0, m1, node0, node1, sn0, sn1, q4, has1, acc0, acc1);
    float4 o0 = bn_relu(acc0, sc, sh);
    store_bf_quad(o0, Xh, Xl, (size_t)node0 * HID + chunk * 16 + q4);
    if (has1) {
        float4 o1 = bn_relu(acc1, sc, sh);
        store_bf_quad(o1, Xh, Xl, (size_t)node1 * HID + chunk * 16 + q4);
    }
}

// variant B: fp32 chunk-major (last layer, feeds pool)
__global__ __launch_bounds__(256) void k_gather_f32(const float* __restrict__ H,
                                                    const int2* __restrict__ meta,
                                                    const int2* __restrict__ edata,
                                                    const int* __restrict__ perm,
                                                    const float* __restrict__ selfn,
                                                    const float* __restrict__ bnscale,
                                                    const float* __restrict__ bnshift,
                                                    float* __restrict__ X) {
    int bid = blockIdx.x;
    int x8 = bid & 7;
    int rest = bid >> 3;
    int phase = (rest >= GNB2) ? 1 : 0;
    int nb = rest - phase * GNB2;
    int chunk = phase * 8 + x8;
    const float* Hc = H + (size_t)chunk * (N_NODES * 16);
    float* Xc = X + (size_t)chunk * (N_NODES * 16);
    int lanegrp = threadIdx.x >> 2;
    int slot0 = nb * 128 + lanegrp;
    int slot1 = slot0 + 64;
    if (slot0 >= N_NODES) return;
    bool has1 = (slot1 < N_NODES);
    int node0 = perm[slot0];
    int node1 = has1 ? perm[slot1] : 0;
    int2 m0 = meta[slot0];
    int2 m1 = has1 ? meta[slot1] : make_int2(0, 0);
    float sn0 = selfn[node0];
    float sn1 = has1 ? selfn[node1] : 0.f;
    int q4 = (threadIdx.x & 3) * 4;
    float4 sc = *(const float4*)(bnscale + chunk * 16 + q4);
    float4 sh = *(const float4*)(bnshift + chunk * 16 + q4);
    float4 acc0, acc1;
    gather_dual(Hc, edata, m0, m1, node0, node1, sn0, sn1, q4, has1, acc0, acc1);
    float4 o0 = bn_relu(acc0, sc, sh);
    f32x4 v0;
    v0.x = o0.x; v0.y = o0.y; v0.z = o0.z; v0.w = o0.w;
    __builtin_nontemporal_store(v0, (f32x4*)(Xc + (size_t)node0 * 16 + q4));
    if (has1) {
        float4 o1 = bn_relu(acc1, sc, sh);
        f32x4 v1;
        v1.x = o1.x; v1.y = o1.y; v1.z = o1.z; v1.w = o1.w;
        __builtin_nontemporal_store(v1, (f32x4*)(Xc + (size_t)node1 * 16 + q4));
    }
}

// ---------------- segmented mean pool (X is chunk-major) ----------------
#define POOL_SPAN 25
__global__ __launch_bounds__(256) void k_pool(const float* __restrict__ X,
                                              const int* __restrict__ batch,
                                              float* __restrict__ pooled,
                                              int* __restrict__ cnt, int N) {
    int n0 = blockIdx.x * POOL_SPAN;
    int c = threadIdx.x;
    const float* Xc = X + (size_t)(c >> 4) * (N_NODES * 16) + (c & 15);
    int nend = min(n0 + POOL_SPAN, N);
    float acc = 0.f;
    int curg = batch[n0];
    int segcnt = 0;
    for (int n = n0; n < nend; ++n) {
        int g = batch[n];
        if (g != curg) {
            atomicAdd(&pooled[(size_t)curg * HID + c], acc);
            if (c == 0) atomicAdd(&cnt[curg], segcnt);
            acc = 0.f;
            segcnt = 0;
            curg = g;
        }
        acc += Xc[(size_t)n * 16];
        ++segcnt;
    }
    atomicAdd(&pooled[(size_t)curg * HID + c], acc);
    if (c == 0) atomicAdd(&cnt[curg], segcnt);
}

// ---------------- MLP head ----------------
__global__ __launch_bounds__(128) void k_mlp(const float* __restrict__ pooled,
                                             const int* __restrict__ cnt,
                                             const float* __restrict__ W1,
                                             const float* __restrict__ b1,
                                             const float* __restrict__ W2,
                                             const float* __restrict__ b2,
                                             float* __restrict__ out) {
    __shared__ float prow[HID];
    __shared__ float hred[2];
    int g = blockIdx.x;
    int j = threadIdx.x;
    prow[j] = pooled[(size_t)g * HID + j];
    prow[j + 128] = pooled[(size_t)g * HID + 128 + j];
    __syncthreads();
    float acc = 0.f;
    #pragma unroll 8
    for (int k = 0; k < HID; ++k) acc += prow[k] * W1[k * 128 + j];
    float inv = 1.0f / fmaxf((float)cnt[g], 1.0f);
    float h = fmaxf(acc * inv + b1[j], 0.f);
    float p = h * W2[j];
    #pragma unroll
    for (int off = 32; off > 0; off >>= 1) p += __shfl_down(p, off, 64);
    if ((j & 63) == 0) hred[j >> 6] = p;
    __syncthreads();
    if (j == 0) out[g] = hred[0] + hred[1] + b2[0];
}

extern "C" void kernel_launch(void* const* d_in, const int* in_sizes, int n_in,
                              void* d_out, int out_size, void* d_ws, size_t ws_size,
                              hipStream_t stream) {
    const float* x      = (const float*)d_in[0];
    const int*   ei     = (const int*)d_in[1];
    const int*   batch  = (const int*)d_in[2];
    const float* convW0 = (const float*)d_in[3];
    const float* convWs = (const float*)d_in[4];
    const float* convB  = (const float*)d_in[5];
    const float* gamma  = (const float*)d_in[6];
    const float* beta   = (const float*)d_in[7];
    const float* mean   = (const float*)d_in[8];
    const float* var    = (const float*)d_in[9];
    const float* lin1W  = (const float*)d_in[10];
    const float* lin1b  = (const float*)d_in[11];
    const float* lin2W  = (const float*)d_in[12];
    const float* lin2b  = (const float*)d_in[13];
    float* out = (float*)d_out;

    const int* src = ei;
    const int* dst = ei + N_EDGES;

    const int WTOT = 128 * 256 + 3 * 256 * 256; // 229376

    float* ws = (float*)d_ws;
    float* xbuf = ws;                                    // N*HID fp32 (layer3 out, chunk-major)
    float* hbuf = xbuf + (size_t)N_NODES * HID;          // N*HID fp32 (H, chunk-major)
    ushort_t* Ahb = (ushort_t*)(hbuf + (size_t)N_NODES * HID); // N*HID
    ushort_t* Alb = Ahb + (size_t)N_NODES * HID;         // N*HID
    ushort_t* WhT = Alb + (size_t)N_NODES * HID;         // WTOT
    ushort_t* WlT = WhT + WTOT;                          // WTOT
    float* dinv    = (float*)(WlT + WTOT);               // N
    float* selfn   = dinv + N_NODES;                     // N
    float* pooled  = selfn + N_NODES;                    // G*HID
    float* bnscale = pooled + (size_t)N_GRAPHS * HID;    // 4*HID
    float* bnshift = bnscale + N_LAYERS * HID;           // 4*HID
    int*   cnt     = (int*)(bnshift + N_LAYERS * HID);   // G
    int*   degi    = cnt + N_GRAPHS;                     // N
    int*   cursor  = degi + N_NODES;                     // N
    int*   perm    = cursor + N_NODES;                   // N
    int*   invperm = perm + N_NODES;                     // N
    int*   bins    = invperm + N_NODES;                  // NBIN
    int*   binstart= bins + NBIN;                        // NBIN
    int*   bincur  = binstart + NBIN;                    // NBIN
    int*   edgebase= bincur + NBIN;                      // NBIN
    int2*  meta    = (int2*)(edgebase + NBIN);           // N int2
    int2*  edata   = meta + N_NODES;                     // E int2

    hipMemsetAsync(degi, 0, (size_t)N_NODES * 4, stream);
    hipMemsetAsync(bins, 0, (size_t)NBIN * 4, stream);
    hipMemsetAsync(pooled, 0, (size_t)N_GRAPHS * HID * 4, stream);
    hipMemsetAsync(cnt, 0, (size_t)N_GRAPHS * 4, stream);

    // CSR build + norms + degree sort (all parallel; closed-form offsets)
    k_deg<<<(N_EDGES + 255) / 256, 256, 0, stream>>>(dst, degi, N_EDGES);
    k_nodenorm<<<(N_NODES + 255) / 256, 256, 0, stream>>>(degi, dinv, selfn, N_NODES);
    k_hist<<<(N_NODES + 255) / 256, 256, 0, stream>>>(degi, bins, N_NODES);
    k_binscan<<<1, 64, 0, stream>>>(bins, binstart, bincur, edgebase);
    k_assign<<<(N_NODES + 255) / 256, 256, 0, stream>>>(degi, binstart, edgebase, bins, bincur,
                                                        perm, invperm, meta, cursor, N_NODES);
    k_fill<<<(N_EDGES + 255) / 256, 256, 0, stream>>>(src, dst, dinv, invperm, meta, cursor,
                                                      edata, N_EDGES);

    // prep
    k_bnprep<<<N_LAYERS, 256, 0, stream>>>(gamma, beta, mean, var, convB, bnscale, bnshift);
    k_splitw<<<(WTOT + 255) / 256, 256, 0, stream>>>(convW0, convWs, WhT, WlT);
    k_splitx<<<(N_NODES * IN_DIM / 4 + 255) / 256, 256, 0, stream>>>(x, Ahb, Alb, N_NODES * IN_DIM / 4);

    dim3 gg((N_NODES + 127) / 128, HID / 128);
    for (int l = 0; l < N_LAYERS; ++l) {
        int K = (l == 0) ? IN_DIM : HID;
        size_t woff = (l == 0) ? 0 : (size_t)(32768 + (l - 1) * 65536);
        k_gemm<<<gg, 256, 0, stream>>>(Ahb, Alb, WhT + woff, WlT + woff, hbuf, K);
        if (l < N_LAYERS - 1)
            k_gather_bf<<<16 * GNB2, 256, 0, stream>>>(hbuf, meta, edata, perm, selfn,
                                                       bnscale + l * HID, bnshift + l * HID,
                                                       Ahb, Alb);
        else
            k_gather_f32<<<16 * GNB2, 256, 0, stream>>>(hbuf, meta, edata, perm, selfn,
                                                        bnscale + l * HID, bnshift + l * HID,
                                                        xbuf);
    }

    k_pool<<<(N_NODES + POOL_SPAN - 1) / POOL_SPAN, 256, 0, stream>>>(xbuf, batch, pooled, cnt, N_NODES);
    k_mlp<<<N_GRAPHS, 128, 0, stream>>>(pooled, cnt, lin1W, lin1b, lin2W, lin2b, out);
}

// Round 14
// 738.845 us; speedup vs baseline: 1.0461x; 1.0461x over previous
//
#include <hip/hip_runtime.h>

#define N_NODES 50000
#define N_EDGES 800000
#define N_GRAPHS 2048
#define IN_DIM 128
#define HID 256
#define N_LAYERS 4
#define BN_EPS 1e-5f
#define NBIN 128

typedef unsigned short ushort_t;
typedef __bf16 bf16x8 __attribute__((ext_vector_type(8)));
typedef float f32x4 __attribute__((ext_vector_type(4)));
typedef unsigned int u32x2 __attribute__((ext_vector_type(2)));

// ---- fp32 -> bf16 (round-to-nearest-even) helpers ----
__device__ __forceinline__ ushort_t f2bf_rn(float x) {
    unsigned int u = __float_as_uint(x);
    u += 0x7FFFu + ((u >> 16) & 1u);
    return (ushort_t)(u >> 16);
}
__device__ __forceinline__ float bf2f(ushort_t h) {
    return __uint_as_float(((unsigned int)h) << 16);
}

// ---- async global->LDS, 16B per lane ----
__device__ __forceinline__ void gl_lds16(const ushort_t* g, ushort_t* l) {
    __builtin_amdgcn_global_load_lds(
        (const __attribute__((address_space(1))) void*)g,
        (__attribute__((address_space(3))) void*)l, 16, 0, 0);
}

// ---------------- degree count ----------------
__global__ void k_deg(const int* __restrict__ dst, int* __restrict__ degi, int E) {
    int e = blockIdx.x * blockDim.x + threadIdx.x;
    if (e < E) atomicAdd(&degi[dst[e]], 1);
}

__global__ void k_nodenorm(const int* __restrict__ degi, float* __restrict__ dinv,
                           float* __restrict__ selfn, int N) {
    int n = blockIdx.x * blockDim.x + threadIdx.x;
    if (n < N) {
        float d = 1.0f + (float)degi[n];
        dinv[n] = 1.0f / sqrtf(d);
        selfn[n] = 1.0f / d;
    }
}

// ---------------- degree histogram (hierarchical) ----------------
__global__ __launch_bounds__(256) void k_hist(const int* __restrict__ degi,
                                              int* __restrict__ bins, int N) {
    __shared__ int lbin[NBIN];
    int t = threadIdx.x;
    if (t < NBIN) lbin[t] = 0;
    __syncthreads();
    int n = blockIdx.x * 256 + t;
    if (n < N) atomicAdd(&lbin[min(degi[n], NBIN - 1)], 1);
    __syncthreads();
    if (t < NBIN && lbin[t] > 0) atomicAdd(&bins[t], lbin[t]);
}

// ---------------- bin prefix (tiny serial, 128 iters) ----------------
__global__ void k_binscan(const int* __restrict__ bins, int* __restrict__ binstart,
                          int* __restrict__ bincur, int* __restrict__ edgebase) {
    if (threadIdx.x == 0) {
        int run = 0, erun = 0;
        for (int d = 0; d < NBIN; ++d) {
            binstart[d] = run;
            bincur[d] = run;
            edgebase[d] = erun;
            run += bins[d];
            erun += bins[d] * d;
        }
    }
}

// ---------------- parallel slot assignment, hierarchical; emits per-slot meta ----------------
// Bin-d edges stored COLUMN-MAJOR: edge j of slot s at edgebase[d] + j*bins[d] + (s-binstart[d]).
// meta[slot] = { eoff, stride | deg<<20 }.
__global__ __launch_bounds__(256) void k_assign(const int* __restrict__ degi,
                                                const int* __restrict__ binstart,
                                                const int* __restrict__ edgebase,
                                                const int* __restrict__ bins,
                                                int* __restrict__ bincur,
                                                int* __restrict__ perm, int* __restrict__ invperm,
                                                int2* __restrict__ meta, int* __restrict__ cursor,
                                                int N) {
    __shared__ int lbin[NBIN];
    __shared__ int lbase[NBIN];
    int t = threadIdx.x;
    if (t < NBIN) lbin[t] = 0;
    __syncthreads();
    int n = blockIdx.x * 256 + t;
    int d = 0, lrank = 0;
    if (n < N) {
        d = min(degi[n], NBIN - 1);
        lrank = atomicAdd(&lbin[d], 1);
    }
    __syncthreads();
    if (t < NBIN && lbin[t] > 0) lbase[t] = atomicAdd(&bincur[t], lbin[t]);
    __syncthreads();
    if (n < N) {
        int slot = lbase[d] + lrank;
        perm[slot] = n;
        invperm[n] = slot;
        int2 m;
        m.x = edgebase[d] + (slot - binstart[d]);
        m.y = bins[d] | (d << 20);
        meta[slot] = m;
        cursor[slot] = 0;
    }
}

// ---------------- CSR fill into bin-interleaved layout ----------------
__global__ void k_fill(const int* __restrict__ src, const int* __restrict__ dst,
                       const float* __restrict__ dinv, const int* __restrict__ invperm,
                       const int2* __restrict__ meta, int* __restrict__ cursor,
                       int2* __restrict__ edata, int E) {
    int e = blockIdx.x * blockDim.x + threadIdx.x;
    if (e >= E) return;
    int s = src[e], d = dst[e];
    int slot = invperm[d];
    int2 m = meta[slot];
    int j = atomicAdd(&cursor[slot], 1);
    int pos = m.x + j * (m.y & 0xFFFFF);
    int2 v;
    v.x = s;
    v.y = __float_as_int(dinv[s] * dinv[d]);
    edata[pos] = v;
}

// ---------------- split x -> bf16 hi/lo ----------------
__global__ __launch_bounds__(256) void k_splitx(const float* __restrict__ x,
                                                ushort_t* __restrict__ Ah,
                                                ushort_t* __restrict__ Al, int total4) {
    int i = blockIdx.x * blockDim.x + threadIdx.x;
    if (i >= total4) return;
    float4 v = ((const float4*)x)[i];
    ushort4 h, l;
    h.x = f2bf_rn(v.x); l.x = f2bf_rn(v.x - bf2f(h.x));
    h.y = f2bf_rn(v.y); l.y = f2bf_rn(v.y - bf2f(h.y));
    h.z = f2bf_rn(v.z); l.z = f2bf_rn(v.z - bf2f(h.z));
    h.w = f2bf_rn(v.w); l.w = f2bf_rn(v.w - bf2f(h.w));
    ((ushort4*)Ah)[i] = h;
    ((ushort4*)Al)[i] = l;
}

// ---------------- split + transpose weights ----------------
__global__ void k_splitw(const float* __restrict__ W0, const float* __restrict__ Ws,
                         ushort_t* __restrict__ Wh, ushort_t* __restrict__ Wl) {
    int i = blockIdx.x * blockDim.x + threadIdx.x;
    const int total = 128 * 256 + 3 * 256 * 256;
    if (i >= total) return;
    float v;
    if (i < 32768) {
        int n = i >> 7, k = i & 127;
        v = W0[k * 256 + n];
    } else {
        int t = i - 32768;
        int l = t >> 16;
        int r = t & 65535;
        int n = r >> 8, k = r & 255;
        v = Ws[l * 65536 + k * 256 + n];
    }
    ushort_t h = f2bf_rn(v);
    Wh[i] = h;
    Wl[i] = f2bf_rn(v - bf2f(h));
}

// ---------------- MFMA split-bf16 GEMM (chunk-major output) ----------------
__global__ __launch_bounds__(256) void k_gemm(const ushort_t* __restrict__ Ah,
                                              const ushort_t* __restrict__ Al,
                                              const ushort_t* __restrict__ Wh,
                                              const ushort_t* __restrict__ Wl,
                                              float* __restrict__ H, int K) {
    __shared__ ushort_t sm[4 * 128 * 32];
    ushort_t* tAh = sm;
    ushort_t* tAl = sm + 4096;
    ushort_t* tWh = sm + 8192;
    ushort_t* tWl = sm + 12288;

    int tid = threadIdx.x;
    int lane = tid & 63;
    int w = tid >> 6;
    int wrow = w & 1, wcol = w >> 1;
    int row0 = blockIdx.x * 128;
    int col0 = blockIdx.y * 128;

    const ushort_t* gsrc = (w == 0) ? Ah : (w == 1) ? Al : (w == 2) ? Wh : Wl;
    int rbase = (w < 2) ? row0 : col0;
    int rlimit = (w < 2) ? N_NODES : (col0 + 128);
    ushort_t* ldst = sm + w * 4096;
    int srow = lane >> 2;
    int sch = lane & 3;

    f32x4 acc[4][4] = {};
    int m = lane & 15, q = lane >> 4;

    for (int k0 = 0; k0 < K; k0 += 32) {
        #pragma unroll
        for (int i = 0; i < 8; ++i) {
            int r = i * 16 + srow;
            int grow = rbase + r;
            int gch = sch ^ (r & 3);
            if (grow < rlimit)
                gl_lds16(gsrc + (size_t)grow * K + k0 + gch * 8, ldst + i * 512);
        }
        __syncthreads();

        bf16x8 ahf[4], alf[4], whf[4], wlf[4];
        #pragma unroll
        for (int r = 0; r < 4; ++r) {
            int rr = wrow * 64 + r * 16 + m;
            int off = rr * 32 + ((q ^ (rr & 3)) << 3);
            ahf[r] = *(const bf16x8*)(tAh + off);
            alf[r] = *(const bf16x8*)(tAl + off);
        }
        #pragma unroll
        for (int c = 0; c < 4; ++c) {
            int nn = wcol * 64 + c * 16 + m;
            int off = nn * 32 + ((q ^ (nn & 3)) << 3);
            whf[c] = *(const bf16x8*)(tWh + off);
            wlf[c] = *(const bf16x8*)(tWl + off);
        }
        #pragma unroll
        for (int r = 0; r < 4; ++r)
            #pragma unroll
            for (int c = 0; c < 4; ++c) {
                acc[r][c] = __builtin_amdgcn_mfma_f32_16x16x32_bf16(ahf[r], whf[c], acc[r][c], 0, 0, 0);
                acc[r][c] = __builtin_amdgcn_mfma_f32_16x16x32_bf16(ahf[r], wlf[c], acc[r][c], 0, 0, 0);
                acc[r][c] = __builtin_amdgcn_mfma_f32_16x16x32_bf16(alf[r], whf[c], acc[r][c], 0, 0, 0);
            }
        __syncthreads();
    }

    #pragma unroll
    for (int r = 0; r < 4; ++r) {
        int mrow = row0 + wrow * 64 + r * 16 + (lane >> 4) * 4;
        #pragma unroll
        for (int c = 0; c < 4; ++c) {
            int n = col0 + wcol * 64 + c * 16 + (lane & 15);
            float* base = H + (size_t)(n >> 4) * (N_NODES * 16) + (n & 15);
            f32x4 v = acc[r][c];
            #pragma unroll
            for (int g = 0; g < 4; ++g)
                if (mrow + g < N_NODES)
                    base[(size_t)(mrow + g) * 16] = v[g];
        }
    }
}

// ---------------- BN prep (bias folded) ----------------
__global__ void k_bnprep(const float* __restrict__ gamma, const float* __restrict__ beta,
                         const float* __restrict__ mean, const float* __restrict__ var,
                         const float* __restrict__ bias,
                         float* __restrict__ scale, float* __restrict__ shift) {
    int l = blockIdx.x;
    int c = threadIdx.x;
    if (c < HID) {
        float s = gamma[l * HID + c] * rsqrtf(var[l * HID + c] + BN_EPS);
        scale[l * HID + c] = s;
        shift[l * HID + c] = beta[l * HID + c] + (bias[l * HID + c] - mean[l * HID + c]) * s;
    }
}

// ---------------- chunked gather: XCD-affine slices, sorted slots, coalesced edata ----------------
// One chunk per block (3.2 MB slice in XCD L2); unroll 8 => 8 outstanding H lines per wave.
#define GNB 782  // ceil(50000/64) slot-blocks per chunk

#define EDGE_FMA(E, V) \
    { float wght = __int_as_float(E.y); \
      acc.x = fmaf(V.x, wght, acc.x); acc.y = fmaf(V.y, wght, acc.y); \
      acc.z = fmaf(V.z, wght, acc.z); acc.w = fmaf(V.w, wght, acc.w); }

__device__ __forceinline__ float4 gather_quad(const float* __restrict__ Hc,
                                              const int2* __restrict__ edata,
                                              const float* __restrict__ selfn,
                                              float4 sc, float4 sh,
                                              int2 m, int node, int q4) {
    int stride = m.y & 0xFFFFF;
    int deg = m.y >> 20;
    const int2* ep = edata + m.x;
    float sn = selfn[node];
    float4 h = *(const float4*)(Hc + (size_t)node * 16 + q4);
    float4 acc;
    acc.x = h.x * sn; acc.y = h.y * sn; acc.z = h.z * sn; acc.w = h.w * sn;
    int j = 0;
    for (; j + 7 < deg; j += 8) {
        int2 e0 = ep[(size_t)(j + 0) * stride];
        int2 e1 = ep[(size_t)(j + 1) * stride];
        int2 e2 = ep[(size_t)(j + 2) * stride];
        int2 e3 = ep[(size_t)(j + 3) * stride];
        int2 e4 = ep[(size_t)(j + 4) * stride];
        int2 e5 = ep[(size_t)(j + 5) * stride];
        int2 e6 = ep[(size_t)(j + 6) * stride];
        int2 e7 = ep[(size_t)(j + 7) * stride];
        float4 v0 = *(const float4*)(Hc + (size_t)e0.x * 16 + q4);
        float4 v1 = *(const float4*)(Hc + (size_t)e1.x * 16 + q4);
        float4 v2 = *(const float4*)(Hc + (size_t)e2.x * 16 + q4);
        float4 v3 = *(const float4*)(Hc + (size_t)e3.x * 16 + q4);
        float4 v4 = *(const float4*)(Hc + (size_t)e4.x * 16 + q4);
        float4 v5 = *(const float4*)(Hc + (size_t)e5.x * 16 + q4);
        float4 v6 = *(const float4*)(Hc + (size_t)e6.x * 16 + q4);
        float4 v7 = *(const float4*)(Hc + (size_t)e7.x * 16 + q4);
        EDGE_FMA(e0, v0) EDGE_FMA(e1, v1) EDGE_FMA(e2, v2) EDGE_FMA(e3, v3)
        EDGE_FMA(e4, v4) EDGE_FMA(e5, v5) EDGE_FMA(e6, v6) EDGE_FMA(e7, v7)
    }
    for (; j + 3 < deg; j += 4) {
        int2 e0 = ep[(size_t)(j + 0) * stride];
        int2 e1 = ep[(size_t)(j + 1) * stride];
        int2 e2 = ep[(size_t)(j + 2) * stride];
        int2 e3 = ep[(size_t)(j + 3) * stride];
        float4 v0 = *(const float4*)(Hc + (size_t)e0.x * 16 + q4);
        float4 v1 = *(const float4*)(Hc + (size_t)e1.x * 16 + q4);
        float4 v2 = *(const float4*)(Hc + (size_t)e2.x * 16 + q4);
        float4 v3 = *(const float4*)(Hc + (size_t)e3.x * 16 + q4);
        EDGE_FMA(e0, v0) EDGE_FMA(e1, v1) EDGE_FMA(e2, v2) EDGE_FMA(e3, v3)
    }
    for (; j < deg; ++j) {
        int2 e0 = ep[(size_t)j * stride];
        float4 v0 = *(const float4*)(Hc + (size_t)e0.x * 16 + q4);
        EDGE_FMA(e0, v0)
    }
    float4 o;
    o.x = fmaxf(fmaf(acc.x, sc.x, sh.x), 0.f);
    o.y = fmaxf(fmaf(acc.y, sc.y, sh.y), 0.f);
    o.z = fmaxf(fmaf(acc.z, sc.z, sh.z), 0.f);
    o.w = fmaxf(fmaf(acc.w, sc.w, sh.w), 0.f);
    return o;
}

// variant A: bf16 hi/lo node-major (feeds next GEMM)
__global__ __launch_bounds__(256) void k_gather_bf(const float* __restrict__ H,
                                                   const int2* __restrict__ meta,
                                                   const int2* __restrict__ edata,
                                                   const int* __restrict__ perm,
                                                   const float* __restrict__ selfn,
                                                   const float* __restrict__ bnscale,
                                                   const float* __restrict__ bnshift,
                                                   ushort_t* __restrict__ Xh,
                                                   ushort_t* __restrict__ Xl) {
    int bid = blockIdx.x;
    int x8 = bid & 7;
    int rest = bid >> 3;
    int phase = (rest >= GNB) ? 1 : 0;
    int nb = rest - phase * GNB;
    int chunk = phase * 8 + x8;
    const float* Hc = H + (size_t)chunk * (N_NODES * 16);
    int slot = nb * 64 + (threadIdx.x >> 2);
    if (slot >= N_NODES) return;
    int node = perm[slot];
    int2 m = meta[slot];
    int q4 = (threadIdx.x & 3) * 4;
    float4 sc = *(const float4*)(bnscale + chunk * 16 + q4);
    float4 sh = *(const float4*)(bnshift + chunk * 16 + q4);
    float4 o = gather_quad(Hc, edata, selfn, sc, sh, m, node, q4);
    ushort4 h, l;
    h.x = f2bf_rn(o.x); l.x = f2bf_rn(o.x - bf2f(h.x));
    h.y = f2bf_rn(o.y); l.y = f2bf_rn(o.y - bf2f(h.y));
    h.z = f2bf_rn(o.z); l.z = f2bf_rn(o.z - bf2f(h.z));
    h.w = f2bf_rn(o.w); l.w = f2bf_rn(o.w - bf2f(h.w));
    size_t oi = (size_t)node * HID + chunk * 16 + q4;
    u32x2 hv, lv;
    hv.x = ((unsigned int)h.y << 16) | h.x;
    hv.y = ((unsigned int)h.w << 16) | h.z;
    lv.x = ((unsigned int)l.y << 16) | l.x;
    lv.y = ((unsigned int)l.w << 16) | l.z;
    __builtin_nontemporal_store(hv, (u32x2*)(Xh + oi));
    __builtin_nontemporal_store(lv, (u32x2*)(Xl + oi));
}

// variant B: fp32 chunk-major (last layer, feeds pool)
__global__ __launch_bounds__(256) void k_gather_f32(const float* __restrict__ H,
                                                    const int2* __restrict__ meta,
                                                    const int2* __restrict__ edata,
                                                    const int* __restrict__ perm,
                                                    const float* __restrict__ selfn,
                                                    const float* __restrict__ bnscale,
                                                    const float* __restrict__ bnshift,
                                                    float* __restrict__ X) {
    int bid = blockIdx.x;
    int x8 = bid & 7;
    int rest = bid >> 3;
    int phase = (rest >= GNB) ? 1 : 0;
    int nb = rest - phase * GNB;
    int chunk = phase * 8 + x8;
    const float* Hc = H + (size_t)chunk * (N_NODES * 16);
    float* Xc = X + (size_t)chunk * (N_NODES * 16);
    int slot = nb * 64 + (threadIdx.x >> 2);
    if (slot >= N_NODES) return;
    int node = perm[slot];
    int2 m = meta[slot];
    int q4 = (threadIdx.x & 3) * 4;
    float4 sc = *(const float4*)(bnscale + chunk * 16 + q4);
    float4 sh = *(const float4*)(bnshift + chunk * 16 + q4);
    float4 o = gather_quad(Hc, edata, selfn, sc, sh, m, node, q4);
    f32x4 ov;
    ov.x = o.x; ov.y = o.y; ov.z = o.z; ov.w = o.w;
    __builtin_nontemporal_store(ov, (f32x4*)(Xc + (size_t)node * 16 + q4));
}

// ---------------- segmented mean pool (X is chunk-major) ----------------
#define POOL_SPAN 25
__global__ __launch_bounds__(256) void k_pool(const float* __restrict__ X,
                                              const int* __restrict__ batch,
                                              float* __restrict__ pooled,
                                              int* __restrict__ cnt, int N) {
    int n0 = blockIdx.x * POOL_SPAN;
    int c = threadIdx.x;
    const float* Xc = X + (size_t)(c >> 4) * (N_NODES * 16) + (c & 15);
    int nend = min(n0 + POOL_SPAN, N);
    float acc = 0.f;
    int curg = batch[n0];
    int segcnt = 0;
    for (int n = n0; n < nend; ++n) {
        int g = batch[n];
        if (g != curg) {
            atomicAdd(&pooled[(size_t)curg * HID + c], acc);
            if (c == 0) atomicAdd(&cnt[curg], segcnt);
            acc = 0.f;
            segcnt = 0;
            curg = g;
        }
        acc += Xc[(size_t)n * 16];
        ++segcnt;
    }
    atomicAdd(&pooled[(size_t)curg * HID + c], acc);
    if (c == 0) atomicAdd(&cnt[curg], segcnt);
}

// ---------------- MLP head ----------------
__global__ __launch_bounds__(128) void k_mlp(const float* __restrict__ pooled,
                                             const int* __restrict__ cnt,
                                             const float* __restrict__ W1,
                                             const float* __restrict__ b1,
                                             const float* __restrict__ W2,
                                             const float* __restrict__ b2,
                                             float* __restrict__ out) {
    __shared__ float prow[HID];
    __shared__ float hred[2];
    int g = blockIdx.x;
    int j = threadIdx.x;
    prow[j] = pooled[(size_t)g * HID + j];
    prow[j + 128] = pooled[(size_t)g * HID + 128 + j];
    __syncthreads();
    float acc = 0.f;
    #pragma unroll 8
    for (int k = 0; k < HID; ++k) acc += prow[k] * W1[k * 128 + j];
    float inv = 1.0f / fmaxf((float)cnt[g], 1.0f);
    float h = fmaxf(acc * inv + b1[j], 0.f);
    float p = h * W2[j];
    #pragma unroll
    for (int off = 32; off > 0; off >>= 1) p += __shfl_down(p, off, 64);
    if ((j & 63) == 0) hred[j >> 6] = p;
    __syncthreads();
    if (j == 0) out[g] = hred[0] + hred[1] + b2[0];
}

extern "C" void kernel_launch(void* const* d_in, const int* in_sizes, int n_in,
                              void* d_out, int out_size, void* d_ws, size_t ws_size,
                              hipStream_t stream) {
    const float* x      = (const float*)d_in[0];
    const int*   ei     = (const int*)d_in[1];
    const int*   batch  = (const int*)d_in[2];
    const float* convW0 = (const float*)d_in[3];
    const float* convWs = (const float*)d_in[4];
    const float* convB  = (const float*)d_in[5];
    const float* gamma  = (const float*)d_in[6];
    const float* beta   = (const float*)d_in[7];
    const float* mean   = (const float*)d_in[8];
    const float* var    = (const float*)d_in[9];
    const float* lin1W  = (const float*)d_in[10];
    const float* lin1b  = (const float*)d_in[11];
    const float* lin2W  = (const float*)d_in[12];
    const float* lin2b  = (const float*)d_in[13];
    float* out = (float*)d_out;

    const int* src = ei;
    const int* dst = ei + N_EDGES;

    const int WTOT = 128 * 256 + 3 * 256 * 256; // 229376

    float* ws = (float*)d_ws;
    float* xbuf = ws;                                    // N*HID fp32 (layer3 out, chunk-major)
    float* hbuf = xbuf + (size_t)N_NODES * HID;          // N*HID fp32 (H, chunk-major)
    ushort_t* Ahb = (ushort_t*)(hbuf + (size_t)N_NODES * HID); // N*HID
    ushort_t* Alb = Ahb + (size_t)N_NODES * HID;         // N*HID
    ushort_t* WhT = Alb + (size_t)N_NODES * HID;         // WTOT
    ushort_t* WlT = WhT + WTOT;                          // WTOT
    float* dinv    = (float*)(WlT + WTOT);               // N
    float* selfn   = dinv + N_NODES;                     // N
    float* pooled  = selfn + N_NODES;                    // G*HID
    float* bnscale = pooled + (size_t)N_GRAPHS * HID;    // 4*HID
    float* bnshift = bnscale + N_LAYERS * HID;           // 4*HID
    int*   cnt     = (int*)(bnshift + N_LAYERS * HID);   // G
    int*   degi    = cnt + N_GRAPHS;                     // N
    int*   cursor  = degi + N_NODES;                     // N
    int*   perm    = cursor + N_NODES;                   // N
    int*   invperm = perm + N_NODES;                     // N
    int*   bins    = invperm + N_NODES;                  // NBIN
    int*   binstart= bins + NBIN;                        // NBIN
    int*   bincur  = binstart + NBIN;                    // NBIN
    int*   edgebase= bincur + NBIN;                      // NBIN
    int2*  meta    = (int2*)(edgebase + NBIN);           // N int2
    int2*  edata   = meta + N_NODES;                     // E int2

    hipMemsetAsync(degi, 0, (size_t)N_NODES * 4, stream);
    hipMemsetAsync(bins, 0, (size_t)NBIN * 4, stream);
    hipMemsetAsync(pooled, 0, (size_t)N_GRAPHS * HID * 4, stream);
    hipMemsetAsync(cnt, 0, (size_t)N_GRAPHS * 4, stream);

    // CSR build + norms + degree sort (all parallel; closed-form offsets)
    k_deg<<<(N_EDGES + 255) / 256, 256, 0, stream>>>(dst, degi, N_EDGES);
    k_nodenorm<<<(N_NODES + 255) / 256, 256, 0, stream>>>(degi, dinv, selfn, N_NODES);
    k_hist<<<(N_NODES + 255) / 256, 256, 0, stream>>>(degi, bins, N_NODES);
    k_binscan<<<1, 64, 0, stream>>>(bins, binstart, bincur, edgebase);
    k_assign<<<(N_NODES + 255) / 256, 256, 0, stream>>>(degi, binstart, edgebase, bins, bincur,
                                                        perm, invperm, meta, cursor, N_NODES);
    k_fill<<<(N_EDGES + 255) / 256, 256, 0, stream>>>(src, dst, dinv, invperm, meta, cursor,
                                                      edata, N_EDGES);

    // prep
    k_bnprep<<<N_LAYERS, 256, 0, stream>>>(gamma, beta, mean, var, convB, bnscale, bnshift);
    k_splitw<<<(WTOT + 255) / 256, 256, 0, stream>>>(convW0, convWs, WhT, WlT);
    k_splitx<<<(N_NODES * IN_DIM / 4 + 255) / 256, 256, 0, stream>>>(x, Ahb, Alb, N_NODES * IN_DIM / 4);

    dim3 gg((N_NODES + 127) / 128, HID / 128);
    for (int l = 0; l < N_LAYERS; ++l) {
        int K = (l == 0) ? IN_DIM : HID;
        size_t woff = (l == 0) ? 0 : (size_t)(32768 + (l - 1) * 65536);
        k_gemm<<<gg, 256, 0, stream>>>(Ahb, Alb, WhT + woff, WlT + woff, hbuf, K);
        if (l < N_LAYERS - 1)
            k_gather_bf<<<16 * GNB, 256, 0, stream>>>(hbuf, meta, edata, perm, selfn,
                                                      bnscale + l * HID, bnshift + l * HID,
                                                      Ahb, Alb);
        else
            k_gather_f32<<<16 * GNB, 256, 0, stream>>>(hbuf, meta, edata, perm, selfn,
                                                       bnscale + l * HID, bnshift + l * HID,
                                                       xbuf);
    }

    k_pool<<<(N_NODES + POOL_SPAN - 1) / POOL_SPAN, 256, 0, stream>>>(xbuf, batch, pooled, cnt, N_NODES);
    k_mlp<<<N_GRAPHS, 128, 0, stream>>>(pooled, cnt, lin1W, lin1b, lin2W, lin2b, out);
}